// Round 10
// baseline (406.335 us; speedup 1.0000x reference)
//
#include <hip/hip_runtime.h>
#include <hip/hip_cooperative_groups.h>
#include <hip/hip_bf16.h>

namespace cg = cooperative_groups;

#define NR 512
#define DF 576
#define LOG2E 1.4426950408889634f

#if __has_builtin(__builtin_amdgcn_exp2f)
#define EXP2F __builtin_amdgcn_exp2f
#else
#define EXP2F exp2f
#endif

typedef short bf16x8 __attribute__((ext_vector_type(8)));
typedef float f32x4 __attribute__((ext_vector_type(4)));
typedef unsigned short u16x8 __attribute__((ext_vector_type(8)));

static __device__ __forceinline__ unsigned short f2bf(float f) {
    unsigned int u = __builtin_bit_cast(unsigned int, f);
    unsigned int r = u + 0x7FFFu + ((u >> 16) & 1u);
    return (unsigned short)(r >> 16);
}
static __device__ __forceinline__ float bf2f(unsigned short h) {
    return __builtin_bit_cast(float, ((unsigned int)h) << 16);
}

// Workspace layout (bytes)
#define PT_OFF  0
#define XFH_OFF 10616832
#define XFL_OFF 11206656
#define WFH_OFF 11796480
#define WFL_OFF 13787136
#define WF_PER_W 331776            // elems per w per plane

#define M_NODES 32
#define CHUNKS  16
#define JPC     36
#define CSTRIDE 19

// ---------------------------------------------------------------------------
// Phase 1: fp32 -> bf16 hi/lo planes in MFMA frag order.  161280 tasks.
// ---------------------------------------------------------------------------
static __device__ __forceinline__ void phase_prep(
    int t, const float* __restrict__ X,
    const float* __restrict__ Wq, const float* __restrict__ Wk,
    const float* __restrict__ Wv,
    unsigned short* __restrict__ XFh, unsigned short* __restrict__ XFl,
    unsigned short* __restrict__ WFh, unsigned short* __restrict__ WFl)
{
    if (t >= 161280) return;
    const float* src; unsigned short *dh, *dl; int flat;
    if (t < 36864) { src = X; dh = XFh; dl = XFl; flat = t * 8; }
    else {
        const int tw = t - 36864;
        const int w  = tw / 41472;
        const int r  = tw - w * 41472;
        src = (w == 0) ? Wq : (w == 1) ? Wk : Wv;
        dh = WFh + (size_t)w * WF_PER_W;
        dl = WFl + (size_t)w * WF_PER_W;
        flat = r * 8;
    }
    const int row  = flat / DF;
    const int k    = flat - row * DF;
    const int fr   = row >> 4;
    const int ks   = k >> 5;
    const int lane = (row & 15) + 16 * ((k & 31) >> 3);
    const int off  = ((fr * 18 + ks) * 64 + lane) * 8;

    const float4 v0 = *reinterpret_cast<const float4*>(src + (size_t)row * DF + k);
    const float4 v1 = *reinterpret_cast<const float4*>(src + (size_t)row * DF + k + 4);
    float fv[8] = {v0.x, v0.y, v0.z, v0.w, v1.x, v1.y, v1.z, v1.w};
    u16x8 h, l;
#pragma unroll
    for (int e = 0; e < 8; ++e) {
        unsigned short hh = f2bf(fv[e]);
        h[e] = hh;
        l[e] = f2bf(fv[e] - bf2f(hh));
    }
    *reinterpret_cast<u16x8*>(dh + off) = h;
    *reinterpret_cast<u16x8*>(dl + off) = l;
}

// ---------------------------------------------------------------------------
// Phase 2: split-K(3) GEMM, LDS-free.  2592 wave-jobs, 32x32 tile each.
// 2 accumulator chains: hh and merged cross cx = ah*bl + al*bh.
// ---------------------------------------------------------------------------
static __device__ __forceinline__ void phase_gemm(
    int wvg, int lane,
    const unsigned short* __restrict__ XFh, const unsigned short* __restrict__ XFl,
    const unsigned short* __restrict__ WFh, const unsigned short* __restrict__ WFl,
    float* __restrict__ PT)
{
    if (wvg >= 2592) return;
    const int w    = wvg / 864;
    const int r1   = wvg - w * 864;
    const int kc   = r1 / 288;
    const int r2   = r1 - kc * 288;
    const int rowt = r2 / 18;
    const int colt = r2 - rowt * 18;

    const unsigned short* wfh = WFh + (size_t)w * WF_PER_W;
    const unsigned short* wfl = WFl + (size_t)w * WF_PER_W;

    const int kbase = kc * 6 * 512;
    const int a0 = (rowt * 2    ) * 9216 + kbase + lane * 8;
    const int a1 = (rowt * 2 + 1) * 9216 + kbase + lane * 8;
    const int b0 = (colt * 2    ) * 9216 + kbase + lane * 8;
    const int b1 = (colt * 2 + 1) * 9216 + kbase + lane * 8;

    f32x4 hh[2][2] = {{{0.f,0.f,0.f,0.f},{0.f,0.f,0.f,0.f}},
                      {{0.f,0.f,0.f,0.f},{0.f,0.f,0.f,0.f}}};
    f32x4 cx[2][2] = {{{0.f,0.f,0.f,0.f},{0.f,0.f,0.f,0.f}},
                      {{0.f,0.f,0.f,0.f},{0.f,0.f,0.f,0.f}}};

#pragma unroll
    for (int s = 0; s < 6; ++s) {
        const int o = s * 512;
        bf16x8 ah0 = *reinterpret_cast<const bf16x8*>(XFh + a0 + o);
        bf16x8 ah1 = *reinterpret_cast<const bf16x8*>(XFh + a1 + o);
        bf16x8 al0 = *reinterpret_cast<const bf16x8*>(XFl + a0 + o);
        bf16x8 al1 = *reinterpret_cast<const bf16x8*>(XFl + a1 + o);
        bf16x8 bh0 = *reinterpret_cast<const bf16x8*>(wfh + b0 + o);
        bf16x8 bh1 = *reinterpret_cast<const bf16x8*>(wfh + b1 + o);
        bf16x8 bl0 = *reinterpret_cast<const bf16x8*>(wfl + b0 + o);
        bf16x8 bl1 = *reinterpret_cast<const bf16x8*>(wfl + b1 + o);

        hh[0][0] = __builtin_amdgcn_mfma_f32_16x16x32_bf16(ah0, bh0, hh[0][0], 0, 0, 0);
        hh[0][1] = __builtin_amdgcn_mfma_f32_16x16x32_bf16(ah0, bh1, hh[0][1], 0, 0, 0);
        hh[1][0] = __builtin_amdgcn_mfma_f32_16x16x32_bf16(ah1, bh0, hh[1][0], 0, 0, 0);
        hh[1][1] = __builtin_amdgcn_mfma_f32_16x16x32_bf16(ah1, bh1, hh[1][1], 0, 0, 0);
        cx[0][0] = __builtin_amdgcn_mfma_f32_16x16x32_bf16(ah0, bl0, cx[0][0], 0, 0, 0);
        cx[0][1] = __builtin_amdgcn_mfma_f32_16x16x32_bf16(ah0, bl1, cx[0][1], 0, 0, 0);
        cx[1][0] = __builtin_amdgcn_mfma_f32_16x16x32_bf16(ah1, bl0, cx[1][0], 0, 0, 0);
        cx[1][1] = __builtin_amdgcn_mfma_f32_16x16x32_bf16(ah1, bl1, cx[1][1], 0, 0, 0);
        cx[0][0] = __builtin_amdgcn_mfma_f32_16x16x32_bf16(al0, bh0, cx[0][0], 0, 0, 0);
        cx[0][1] = __builtin_amdgcn_mfma_f32_16x16x32_bf16(al0, bh1, cx[0][1], 0, 0, 0);
        cx[1][0] = __builtin_amdgcn_mfma_f32_16x16x32_bf16(al1, bh0, cx[1][0], 0, 0, 0);
        cx[1][1] = __builtin_amdgcn_mfma_f32_16x16x32_bf16(al1, bh1, cx[1][1], 0, 0, 0);
    }

    float* P = PT + (size_t)(kc * 3 + w) * NR * DF;
#pragma unroll
    for (int ni = 0; ni < 2; ++ni) {
        const int col = colt * 32 + ni * 16 + (lane & 15);
#pragma unroll
        for (int mi = 0; mi < 2; ++mi) {
            const int row0 = rowt * 32 + mi * 16 + (lane >> 4) * 4;
#pragma unroll
            for (int r = 0; r < 4; ++r)
                P[(size_t)(row0 + r) * DF + col] = hh[mi][ni][r] + cx[mi][ni][r];
        }
    }
}

// ---------------------------------------------------------------------------
// Phase 3: rank-1 attention via tilted-mean interpolation (32 nodes),
// fused split-K reduce (+bias).  One row per block, 512 threads; threads
// t<64 also handle columns 512+t.
// ---------------------------------------------------------------------------
static __device__ __forceinline__ void phase_attn(
    int n, int t, const float* __restrict__ PT,
    const float* __restrict__ bq, const float* __restrict__ bk,
    const float* __restrict__ bv, float* __restrict__ out)
{
    __shared__ __align__(16) float4 KV4[CHUNKS * CSTRIDE];
    __shared__ __align__(16) float Pf[DF];
    __shared__ __align__(16) float Pg[DF];
    __shared__ float Rt[M_NODES];
    __shared__ float range[2];

    const size_t pl = (size_t)NR * DF;
    float qq0, qq1 = 0.f;
    {
        const size_t nb = (size_t)n * DF + t;
        qq0 = ((PT[nb] + PT[pl * 3 + nb]) + PT[pl * 6 + nb]) + bq[t];
        const float kv = ((PT[pl + nb] + PT[pl * 4 + nb]) + PT[pl * 7 + nb]) + bk[t];
        const float vv = ((PT[pl * 2 + nb] + PT[pl * 5 + nb]) + PT[pl * 8 + nb]) + bv[t];
        const int c = t / JPC, jl = t - (t / JPC) * JPC;
        float2* dst = reinterpret_cast<float2*>(&KV4[c * CSTRIDE + (jl >> 1)]);
        dst[jl & 1] = make_float2(kv * LOG2E, vv);
        Pf[t] = qq0;
    }
    if (t < 64) {
        const int j = 512 + t;
        const size_t nb = (size_t)n * DF + j;
        qq1 = ((PT[nb] + PT[pl * 3 + nb]) + PT[pl * 6 + nb]) + bq[j];
        const float kv = ((PT[pl + nb] + PT[pl * 4 + nb]) + PT[pl * 7 + nb]) + bk[j];
        const float vv = ((PT[pl * 2 + nb] + PT[pl * 5 + nb]) + PT[pl * 8 + nb]) + bv[j];
        const int c = j / JPC, jl = j - (j / JPC) * JPC;
        float2* dst = reinterpret_cast<float2*>(&KV4[c * CSTRIDE + (jl >> 1)]);
        dst[jl & 1] = make_float2(kv * LOG2E, vv);
        Pf[j] = qq1;
    }
    __syncthreads();

    if (t < 64) {                          // row min/max of q over 576
        float lo = Pf[t], hi = lo;
#pragma unroll
        for (int r = 1; r < 9; ++r) {
            float v = Pf[t + 64 * r];
            lo = fminf(lo, v); hi = fmaxf(hi, v);
        }
#pragma unroll
        for (int s = 32; s; s >>= 1) {
            lo = fminf(lo, __shfl_xor(lo, s, 64));
            hi = fmaxf(hi, __shfl_xor(hi, s, 64));
        }
        if (t == 0) { range[0] = lo; range[1] = hi; }
    }
    __syncthreads();

    const float qmin = range[0], qmax = range[1];
    const float h    = fmaxf((qmax - qmin) * (1.0f / (M_NODES - 5)), 1e-6f);
    const float qlo  = qmin - 2.0f * h;

    const int m = t >> 4;                  // node 0..31
    const int c = t & 15;                  // chunk 0..15
    const float qm = qlo + h * (float)m;
    const float4* kvp = KV4 + c * CSTRIDE;
    float f0 = 0.f, f1 = 0.f, g0 = 0.f, g1 = 0.f;
#pragma unroll
    for (int jj = 0; jj < JPC / 2; ++jj) {
        float4 p = kvp[jj];
        float e0 = EXP2F(qm * p.x);
        float e1 = EXP2F(qm * p.z);
        g0 += e0; g1 += e1;
        f0 = fmaf(e0, p.y, f0);
        f1 = fmaf(e1, p.w, f1);
    }
    __syncthreads();
    Pf[t] = f0 + f1;
    Pg[t] = g0 + g1;
    __syncthreads();

    if (t < M_NODES) {
        const float4* pf4 = reinterpret_cast<const float4*>(Pf) + t * 4;
        const float4* pg4 = reinterpret_cast<const float4*>(Pg) + t * 4;
        float fs = 0.f, gs = 0.f;
#pragma unroll
        for (int i = 0; i < 4; ++i) {
            float4 a = pf4[i], b = pg4[i];
            fs += (a.x + a.y) + (a.z + a.w);
            gs += (b.x + b.y) + (b.z + b.w);
        }
        Rt[t] = fs / gs;
    }
    __syncthreads();

    float qv[2]; int cols[2];
    qv[0] = qq0; cols[0] = t;
    qv[1] = qq1; cols[1] = 512 + t;
    const int ncol = (t < 64) ? 2 : 1;
    for (int ii = 0; ii < ncol; ++ii) {
        const float u = (qv[ii] - qlo) * (1.0f / h);
        int i0 = (int)u;
        i0 = (i0 < 1) ? 1 : (i0 > M_NODES - 3 ? M_NODES - 3 : i0);
        const float tf = u - (float)i0;
        const float a  = Rt[i0 - 1];
        const float b  = Rt[i0];
        const float cc = Rt[i0 + 1];
        const float d  = Rt[i0 + 2];
        const float m0 = 0.5f * (cc - a);
        const float m1 = 0.5f * (d - b);
        const float dd = cc - b;
        out[(size_t)n * DF + cols[ii]] =
            b + tf * (m0 + tf * ((3.f * dd - 2.f * m0 - m1)
                                 + tf * (m0 + m1 - 2.f * dd)));
    }
}

// ---------------------------------------------------------------------------
// Cooperative mega-kernel: prep -> sync -> gemm -> sync -> attn.
// ---------------------------------------------------------------------------
__global__ __launch_bounds__(512, 4) void mega_kernel(
    const float* X, const float* Wq, const float* Wk, const float* Wv,
    const float* bq, const float* bk, const float* bv,
    unsigned short* XFh, unsigned short* XFl,
    unsigned short* WFh, unsigned short* WFl,
    float* PT, float* out)
{
    cg::grid_group grid = cg::this_grid();
    const int tid = threadIdx.x;
    const int bid = blockIdx.x;

    phase_prep(bid * 512 + tid, X, Wq, Wk, Wv, XFh, XFl, WFh, WFl);
    __threadfence();
    grid.sync();

    phase_gemm(bid * 8 + (tid >> 6), tid & 63, XFh, XFl, WFh, WFl, PT);
    __threadfence();
    grid.sync();

    phase_attn(bid, tid, PT, bq, bk, bv, out);
}

// Fallback path: identical phases as separate kernels.
__global__ __launch_bounds__(512) void prep_k(
    const float* X, const float* Wq, const float* Wk, const float* Wv,
    unsigned short* XFh, unsigned short* XFl,
    unsigned short* WFh, unsigned short* WFl)
{
    phase_prep(blockIdx.x * 512 + threadIdx.x, X, Wq, Wk, Wv, XFh, XFl, WFh, WFl);
}
__global__ __launch_bounds__(512, 4) void gemm_k(
    const unsigned short* XFh, const unsigned short* XFl,
    const unsigned short* WFh, const unsigned short* WFl, float* PT)
{
    phase_gemm(blockIdx.x * 8 + (threadIdx.x >> 6), threadIdx.x & 63,
               XFh, XFl, WFh, WFl, PT);
}
__global__ __launch_bounds__(512) void attn_k(
    const float* PT, const float* bq, const float* bk, const float* bv,
    float* out)
{
    phase_attn(blockIdx.x, threadIdx.x, PT, bq, bk, bv, out);
}

// ---------------------------------------------------------------------------
extern "C" void kernel_launch(void* const* d_in, const int* in_sizes, int n_in,
                              void* d_out, int out_size, void* d_ws, size_t ws_size,
                              hipStream_t stream) {
    const float* x  = (const float*)d_in[0];
    const float* Wq = (const float*)d_in[1];
    const float* bq = (const float*)d_in[2];
    const float* Wk = (const float*)d_in[3];
    const float* bk = (const float*)d_in[4];
    const float* Wv = (const float*)d_in[5];
    const float* bv = (const float*)d_in[6];

    char* ws = (char*)d_ws;
    float*          PT  = (float*)(ws + PT_OFF);
    unsigned short* XFh = (unsigned short*)(ws + XFH_OFF);
    unsigned short* XFl = (unsigned short*)(ws + XFL_OFF);
    unsigned short* WFh = (unsigned short*)(ws + WFH_OFF);
    unsigned short* WFl = (unsigned short*)(ws + WFL_OFF);
    float* outp = (float*)d_out;

    void* args[] = {(void*)&x, (void*)&Wq, (void*)&Wk, (void*)&Wv,
                    (void*)&bq, (void*)&bk, (void*)&bv,
                    (void*)&XFh, (void*)&XFl, (void*)&WFh, (void*)&WFl,
                    (void*)&PT, (void*)&outp};
    hipError_t err = hipLaunchCooperativeKernel(
        reinterpret_cast<void*>(mega_kernel), dim3(512), dim3(512),
        args, 0, stream);

    if (err != hipSuccess) {
        // fallback: same phases, three dependent dispatches
        prep_k<<<315, 512, 0, stream>>>(x, Wq, Wk, Wv, XFh, XFl, WFh, WFl);
        gemm_k<<<324, 512, 0, stream>>>(XFh, XFl, WFh, WFl, PT);
        attn_k<<<512, 512, 0, stream>>>(PT, bq, bk, bv, outp);
    }
}

// Round 11
// 24.038 us; speedup vs baseline: 16.9037x; 16.9037x over previous
//
#include <hip/hip_runtime.h>
#include <hip/hip_bf16.h>

#define NR 512
#define DF 576
#define LOG2E 1.4426950408889634f

#if __has_builtin(__builtin_amdgcn_exp2f)
#define EXP2F __builtin_amdgcn_exp2f
#else
#define EXP2F exp2f
#endif

typedef _Float16 f16x8 __attribute__((ext_vector_type(8)));
typedef float f32x4 __attribute__((ext_vector_type(4)));
typedef unsigned short u16x8 __attribute__((ext_vector_type(8)));

// Workspace layout (bytes):
//  PT[kc(3)][w(3)][512][576] fp32 partials : 10,616,832
//  XF fp16 frag plane                      : 589,824
//  WF fp16 frag plane (3 w's)              : 1,990,656
#define PT_OFF  0
#define XF_OFF  10616832
#define WF_OFF  11206656
#define WF_PER_W 331776        // elems per w (36*18*64*8)

// ---------------------------------------------------------------------------
// Kernel 0: fp32 -> fp16 planes in MFMA fragment order.
//   fr=row>>4, ks=k>>5, lane=(row&15)+16*((k&31)>>3), j=k&7
// fp16 is safe here: |X|<~5, |W|<=1/24, products well inside range;
// 11-bit mantissa => q-error ~1e-4, output error ~<5e-4 (budget 3e-3).
// ---------------------------------------------------------------------------
__global__ __launch_bounds__(256) void prep_f16_kernel(
    const float* __restrict__ X,
    const float* __restrict__ Wq, const float* __restrict__ Wk,
    const float* __restrict__ Wv,
    unsigned short* __restrict__ XF, unsigned short* __restrict__ WF)
{
    const int z = blockIdx.y;
    const float* src; unsigned short* d; int n8;
    if (z == 0) { src = X; d = XF; n8 = (NR * DF) / 8; }
    else {
        src = (z == 1) ? Wq : (z == 2) ? Wk : Wv;
        d = WF + (size_t)(z - 1) * WF_PER_W;
        n8 = (DF * DF) / 8;
    }
    const int i = blockIdx.x * 256 + threadIdx.x;
    if (i >= n8) return;

    const int flat = i * 8;
    const int row  = flat / DF;
    const int k    = flat - row * DF;
    const int fr   = row >> 4;
    const int ks   = k >> 5;
    const int lane = (row & 15) + 16 * ((k & 31) >> 3);
    const int off  = ((fr * 18 + ks) * 64 + lane) * 8;

    const float4 v0 = *reinterpret_cast<const float4*>(src + (size_t)row * DF + k);
    const float4 v1 = *reinterpret_cast<const float4*>(src + (size_t)row * DF + k + 4);
    float fv[8] = {v0.x, v0.y, v0.z, v0.w, v1.x, v1.y, v1.z, v1.w};
    u16x8 h;
#pragma unroll
    for (int e = 0; e < 8; ++e)
        h[e] = __builtin_bit_cast(unsigned short, (_Float16)fv[e]);
    *reinterpret_cast<u16x8*>(d + off) = h;
}

// ---------------------------------------------------------------------------
// Kernel 1: QKV GEMM, fp16 single-term, LDS-free, split-K(3).
// Grid (9,8,9): x=colt2, y=rowt2, z=w*3+kc; 256 thr = 4 waves 2x2.
// Per wave: 32x32 tile over K-chunk 192 = 6 slices x {4 b128 loads + 4 MFMA
// in 4 independent chains}.  Planes total 2.6 MB -> per-XCD L2 resident.
// ---------------------------------------------------------------------------
__global__ __launch_bounds__(256) void qkv_f16_splitk_kernel(
    const unsigned short* __restrict__ XF, const unsigned short* __restrict__ WF,
    float* __restrict__ PT)
{
    const int w  = blockIdx.z / 3;
    const int kc = blockIdx.z - w * 3;
    const int tid  = threadIdx.x;
    const int lane = tid & 63;
    const int wv   = tid >> 6;
    const int rowt = blockIdx.y * 2 + (wv >> 1);   // 0..15
    const int colt = blockIdx.x * 2 + (wv & 1);    // 0..17

    const unsigned short* wf = WF + (size_t)w * WF_PER_W;

    const int kbase = kc * 6 * 512;
    const int a0 = (rowt * 2    ) * 9216 + kbase + lane * 8;
    const int a1 = (rowt * 2 + 1) * 9216 + kbase + lane * 8;
    const int b0 = (colt * 2    ) * 9216 + kbase + lane * 8;
    const int b1 = (colt * 2 + 1) * 9216 + kbase + lane * 8;

    f32x4 acc[2][2] = {{{0.f,0.f,0.f,0.f},{0.f,0.f,0.f,0.f}},
                       {{0.f,0.f,0.f,0.f},{0.f,0.f,0.f,0.f}}};

#pragma unroll
    for (int s = 0; s < 6; ++s) {
        const int o = s * 512;
        f16x8 fa0 = *reinterpret_cast<const f16x8*>(XF + a0 + o);
        f16x8 fa1 = *reinterpret_cast<const f16x8*>(XF + a1 + o);
        f16x8 fb0 = *reinterpret_cast<const f16x8*>(wf + b0 + o);
        f16x8 fb1 = *reinterpret_cast<const f16x8*>(wf + b1 + o);
        acc[0][0] = __builtin_amdgcn_mfma_f32_16x16x32_f16(fa0, fb0, acc[0][0], 0, 0, 0);
        acc[0][1] = __builtin_amdgcn_mfma_f32_16x16x32_f16(fa0, fb1, acc[0][1], 0, 0, 0);
        acc[1][0] = __builtin_amdgcn_mfma_f32_16x16x32_f16(fa1, fb0, acc[1][0], 0, 0, 0);
        acc[1][1] = __builtin_amdgcn_mfma_f32_16x16x32_f16(fa1, fb1, acc[1][1], 0, 0, 0);
    }

    float* P = PT + (size_t)(kc * 3 + w) * NR * DF;
#pragma unroll
    for (int ni = 0; ni < 2; ++ni) {
        const int col = colt * 32 + ni * 16 + (lane & 15);
#pragma unroll
        for (int mi = 0; mi < 2; ++mi) {
            const int row0 = rowt * 32 + mi * 16 + (lane >> 4) * 4;
#pragma unroll
            for (int r = 0; r < 4; ++r)
                P[(size_t)(row0 + r) * DF + col] = acc[mi][ni][r];
        }
    }
}

// ---------------------------------------------------------------------------
// Kernel 2: rank-1 attention via tilted-mean interpolation; fused split-K
// reduce (+bias).  Identical to R9 (for clean attribution).
// ---------------------------------------------------------------------------
#define M_NODES 36
#define CHUNKS  16
#define JPC     36
#define CSTRIDE 19

__global__ __launch_bounds__(576) void attn_interp_kernel(
    const float* __restrict__ PT,
    const float* __restrict__ bq, const float* __restrict__ bk,
    const float* __restrict__ bv,
    float* __restrict__ out)
{
    const int n = blockIdx.x;
    const int t = threadIdx.x;
    const size_t nb = (size_t)n * DF + t;
    const size_t pl = (size_t)NR * DF;

    const float qv = ((PT[nb] + PT[pl * 3 + nb]) + PT[pl * 6 + nb]) + bq[t];
    const float kv = ((PT[pl + nb] + PT[pl * 4 + nb]) + PT[pl * 7 + nb]) + bk[t];
    const float vv = ((PT[pl * 2 + nb] + PT[pl * 5 + nb]) + PT[pl * 8 + nb]) + bv[t];

    __shared__ __align__(16) float4 KV4[CHUNKS * CSTRIDE];
    __shared__ __align__(16) float Pf[DF];
    __shared__ __align__(16) float Pg[DF];
    __shared__ float Rt[M_NODES];
    __shared__ float range[2];

    {
        const int c  = t / JPC;
        const int jl = t - c * JPC;
        float2* dst = reinterpret_cast<float2*>(&KV4[c * CSTRIDE + (jl >> 1)]);
        dst[jl & 1] = make_float2(kv * LOG2E, vv);
    }
    Pf[t] = qv;
    __syncthreads();

    if (t < 64) {
        float lo = Pf[t], hi = lo;
#pragma unroll
        for (int r = 1; r < 9; ++r) {
            float v = Pf[t + 64 * r];
            lo = fminf(lo, v); hi = fmaxf(hi, v);
        }
#pragma unroll
        for (int s = 32; s; s >>= 1) {
            lo = fminf(lo, __shfl_xor(lo, s, 64));
            hi = fmaxf(hi, __shfl_xor(hi, s, 64));
        }
        if (t == 0) { range[0] = lo; range[1] = hi; }
    }
    __syncthreads();

    const float qmin = range[0], qmax = range[1];
    const float h    = fmaxf((qmax - qmin) * (1.0f / (M_NODES - 5)), 1e-6f);
    const float qlo  = qmin - 2.0f * h;

    const int m = t >> 4;
    const int c = t & 15;
    const float qm = qlo + h * (float)m;
    const float4* kvp = KV4 + c * CSTRIDE;
    float f0 = 0.f, f1 = 0.f, g0 = 0.f, g1 = 0.f;
#pragma unroll
    for (int jj = 0; jj < JPC / 2; ++jj) {
        float4 p = kvp[jj];
        float e0 = EXP2F(qm * p.x);
        float e1 = EXP2F(qm * p.z);
        g0 += e0; g1 += e1;
        f0 = fmaf(e0, p.y, f0);
        f1 = fmaf(e1, p.w, f1);
    }
    __syncthreads();
    Pf[t] = f0 + f1;
    Pg[t] = g0 + g1;
    __syncthreads();

    if (t < M_NODES) {
        const float4* pf4 = reinterpret_cast<const float4*>(Pf) + t * 4;
        const float4* pg4 = reinterpret_cast<const float4*>(Pg) + t * 4;
        float fs = 0.f, gs = 0.f;
#pragma unroll
        for (int i = 0; i < 4; ++i) {
            float4 a = pf4[i], b = pg4[i];
            fs += (a.x + a.y) + (a.z + a.w);
            gs += (b.x + b.y) + (b.z + b.w);
        }
        Rt[t] = fs / gs;
    }
    __syncthreads();

    const float u = (qv - qlo) * (1.0f / h);
    int i0 = (int)u;
    i0 = (i0 < 1) ? 1 : (i0 > M_NODES - 3 ? M_NODES - 3 : i0);
    const float tf = u - (float)i0;
    const float a  = Rt[i0 - 1];
    const float b  = Rt[i0];
    const float cc = Rt[i0 + 1];
    const float d  = Rt[i0 + 2];
    const float m0 = 0.5f * (cc - a);
    const float m1 = 0.5f * (d - b);
    const float dd = cc - b;
    const float r  = b + tf * (m0 + tf * ((3.f * dd - 2.f * m0 - m1)
                                          + tf * (m0 + m1 - 2.f * dd)));
    out[(size_t)n * DF + t] = r;
}

// ---------------------------------------------------------------------------
extern "C" void kernel_launch(void* const* d_in, const int* in_sizes, int n_in,
                              void* d_out, int out_size, void* d_ws, size_t ws_size,
                              hipStream_t stream) {
    const float* x  = (const float*)d_in[0];
    const float* Wq = (const float*)d_in[1];
    const float* bq = (const float*)d_in[2];
    const float* Wk = (const float*)d_in[3];
    const float* bk = (const float*)d_in[4];
    const float* Wv = (const float*)d_in[5];
    const float* bv = (const float*)d_in[6];

    char* ws = (char*)d_ws;
    float*          PT = (float*)(ws + PT_OFF);
    unsigned short* XF = (unsigned short*)(ws + XF_OFF);
    unsigned short* WF = (unsigned short*)(ws + WF_OFF);

    prep_f16_kernel<<<dim3(162, 4, 1), 256, 0, stream>>>(
        x, Wq, Wk, Wv, XF, WF);

    qkv_f16_splitk_kernel<<<dim3(9, 8, 9), 256, 0, stream>>>(XF, WF, PT);

    attn_interp_kernel<<<NR, DF, 0, stream>>>(PT, bq, bk, bv, (float*)d_out);
}